// Round 6
// baseline (205.709 us; speedup 1.0000x reference)
//
#include <hip/hip_runtime.h>

// B=4, S=1024, E=1024, H=16, D=64. All GEMMs are 4096x1024x1024 (A MxK row-major,
// W NxK row-major => C = A * W^T + bias).

typedef _Float16 v8h __attribute__((ext_vector_type(8)));
typedef _Float16 v4h __attribute__((ext_vector_type(4)));
typedef float    v4f __attribute__((ext_vector_type(4)));

#define MFMA_F16(A_, B_, C_) __builtin_amdgcn_mfma_f32_16x16x32_f16(A_, B_, C_, 0, 0, 0)

__device__ __forceinline__ void async_copy16(const void* g, void* l) {
    __builtin_amdgcn_global_load_lds(
        (const __attribute__((address_space(1))) void*)g,
        (__attribute__((address_space(3))) void*)l, 16, 0, 0);
}

__device__ __forceinline__ v8h cat4(v4h a, v4h b) {
    return __builtin_shufflevector(a, b, 0, 1, 2, 3, 4, 5, 6, 7);
}

// ---------------- fp32 -> fp16 conversion (5 tensors, one launch) ----------------
__global__ __launch_bounds__(256) void cvt5_kernel(
    const float* __restrict__ s0, const float* __restrict__ s1,
    const float* __restrict__ s2, const float* __restrict__ s3,
    const float* __restrict__ s4,
    _Float16* __restrict__ d0, _Float16* __restrict__ d1,
    _Float16* __restrict__ d2, _Float16* __restrict__ d3,
    _Float16* __restrict__ d4,
    int n0, int n1, int n2, int n3, int n4)
{
    const float* s; _Float16* d; int n;
    switch (blockIdx.y) {
        case 0:  s = s0; d = d0; n = n0; break;
        case 1:  s = s1; d = d1; n = n1; break;
        case 2:  s = s2; d = d2; n = n2; break;
        case 3:  s = s3; d = d3; n = n3; break;
        default: s = s4; d = d4; n = n4; break;
    }
    int i = (blockIdx.x * 256 + threadIdx.x) * 4;
    if (i >= n) return;
    float4 f = *(const float4*)(s + i);
    v4h o = { (_Float16)f.x, (_Float16)f.y, (_Float16)f.z, (_Float16)f.w };
    *(v4h*)(d + i) = o;
}

// ---------------- shared GEMM core: C = A * W^T + bias ----------------
// TM x 128 tile, BK=64, 256 threads (4 waves). TM=128: wave tile 64x64 (acc 4x4);
// TM=64: wave tile 64x32 (acc 4x2) -> 2x the blocks/CU (m132: 2 blk/CU costs ~1.7x).
// XOR-swizzled LDS; staged via global_load_lds 16B/lane; epilogue through per-wave
// LDS scratch for coalesced 16B/lane stores.
// MODE 0: fp16 (B,H,S,D); MODE 1: fp16 transposed (B,H,D,S); MODE 2: fp32 (M,N).
template<int TM, int MODE>
__device__ __forceinline__ void gemm_core(const _Float16* __restrict__ A,
                                          const _Float16* __restrict__ W,
                                          const float* __restrict__ bias,
                                          void* __restrict__ outp,
                                          int row0, int col0)
{
    constexpr int WCOLS = (TM == 128) ? 64 : 32;
    constexpr int NJ = WCOLS / 16;
    constexpr int CH = WCOLS / 8;                    // 16B chunks per scratch row
    constexpr int SC_H = (MODE == 2) ? 4096 : 64 * WCOLS;  // per-wave scratch halves
    constexpr int STG_H = (TM + 128) * 64;
    constexpr int TOT_H = (STG_H > 4 * SC_H) ? STG_H : 4 * SC_H;
    __shared__ __align__(16) _Float16 smem[TOT_H];
    _Float16* As = smem;
    _Float16* Bs = smem + TM * 64;

    const int tid  = threadIdx.x;
    const int wave = tid >> 6, lane = tid & 63;
    const int quad = lane >> 4, n16 = lane & 15;
    const int wm = (TM == 128) ? (wave >> 1) : 0;
    const int wn = (TM == 128) ? (wave & 1) : wave;
    const int rL = lane >> 3, c8 = lane & 7;
    const int lcs = c8 ^ rL;

    v4f acc[4][NJ] = {};

    for (int kb = 0; kb < 1024; kb += 64) {
        __syncthreads();
        #pragma unroll
        for (int p = 0; p < TM / 32; p++) {
            int rg = wave * (TM / 32) + p;
            int row = rg * 8 + rL;
            async_copy16(A + (size_t)(row0 + row) * 1024 + kb + lcs * 8, &As[rg * 512]);
        }
        #pragma unroll
        for (int p = 0; p < 4; p++) {
            int rg = wave * 4 + p;
            int row = rg * 8 + rL;
            async_copy16(W + (size_t)(col0 + row) * 1024 + kb + lcs * 8, &Bs[rg * 512]);
        }
        __syncthreads();
        #pragma unroll
        for (int ks = 0; ks < 64; ks += 32) {
            const int pc = ((ks >> 3) + quad) ^ (n16 & 7);
            v8h af[4], bf[NJ];
            #pragma unroll
            for (int i = 0; i < 4; i++)
                af[i] = *(const v8h*)(&As[(wm * 64 + i * 16 + n16) * 64 + pc * 8]);
            #pragma unroll
            for (int j = 0; j < NJ; j++)
                bf[j] = *(const v8h*)(&Bs[(wn * WCOLS + j * 16 + n16) * 64 + pc * 8]);
            #pragma unroll
            for (int i = 0; i < 4; i++)
                #pragma unroll
                for (int j = 0; j < NJ; j++)
                    acc[i][j] = MFMA_F16(af[i], bf[j], acc[i][j]);
        }
    }

    __syncthreads();                       // staged tiles dead; reuse LDS as scratch
    const int b     = (row0 + wm * 64) >> 10;
    const int srow0 = (row0 + wm * 64) & 1023;
    const int C0    = col0 + wn * WCOLS;

    if (MODE == 0) {                       // [s][d] scratch, coalesced (B,H,S,D) stores
        _Float16* sc = smem + wave * SC_H;
        #pragma unroll
        for (int i = 0; i < 4; i++)
            #pragma unroll
            for (int j = 0; j < NJ; j++)
                #pragma unroll
                for (int r = 0; r < 4; r++) {
                    int rowL = i * 16 + quad * 4 + r, colL = j * 16 + n16;
                    float v = acc[i][j][r] + bias[C0 + colL];
                    sc[rowL * WCOLS + (((colL >> 3) ^ (rowL & (CH - 1))) << 3) + (colL & 7)] =
                        (_Float16)v;
                }
        int h = C0 >> 6, dbase = C0 & 63;
        #pragma unroll
        for (int it = 0; it < CH; it++) {
            int rowR = it * (64 / CH) + (lane / CH), cR = lane & (CH - 1);
            v8h val = *(const v8h*)(&sc[rowR * WCOLS + ((cR ^ (rowR & (CH - 1))) << 3)]);
            *(v8h*)((_Float16*)outp +
                    (((size_t)(b * 16 + h) * 1024 + srow0 + rowR) << 6) + dbase + cR * 8) = val;
        }
    } else if (MODE == 1) {                // [d][s] scratch, coalesced (B,H,D,S) stores
        _Float16* sc = smem + wave * SC_H;
        #pragma unroll
        for (int i = 0; i < 4; i++)
            #pragma unroll
            for (int j = 0; j < NJ; j++) {
                int colL = j * 16 + n16;
                int c16 = i * 2 + (quad >> 1);
                v4h pk;
                #pragma unroll
                for (int r = 0; r < 4; r++)
                    pk[r] = (_Float16)(acc[i][j][r] + bias[C0 + colL]);
                *(v4h*)(&sc[colL * 64 + ((c16 ^ (colL & 7)) << 3) + (quad & 1) * 4]) = pk;
            }
        #pragma unroll
        for (int it = 0; it < CH; it++) {
            int dR = it * 8 + (lane >> 3), scn = lane & 7;
            v8h val = *(const v8h*)(&sc[dR * 64 + ((scn ^ (dR & 7)) << 3)]);
            int cg = C0 + dR;
            int h = cg >> 6, dl = cg & 63;
            *(v8h*)((_Float16*)outp +
                    ((size_t)((b * 16 + h) * 64 + dl) << 10) + srow0 + scn * 8) = val;
        }
    } else {                               // MODE 2 (TM=64): fp32 [m][n], wave tile 64x32
        float* sc = (float*)smem + wave * 2048;
        #pragma unroll
        for (int i = 0; i < 4; i++)
            #pragma unroll
            for (int j = 0; j < 2; j++)
                #pragma unroll
                for (int r = 0; r < 4; r++) {
                    int rowL = i * 16 + quad * 4 + r, colL = j * 16 + n16;
                    sc[rowL * 32 + (((colL >> 2) ^ (rowL & 7)) << 2) + (colL & 3)] =
                        acc[i][j][r] + bias[col0 + wn * 32 + colL];
                }
        #pragma unroll
        for (int it = 0; it < 8; it++) {
            int rowR = it * 8 + (lane >> 3), cR = lane & 7;
            v4f val = *(const v4f*)(&sc[rowR * 32 + ((cR ^ (rowR & 7)) << 2)]);
            *(v4f*)((float*)outp + (size_t)(row0 + rowR) * 1024 + col0 + wn * 32 + cR * 4) = val;
        }
    }
}

// 1024 blocks (4/CU). XCD keyed on (z, y-group): XCD k -> z=k&1, y in 16 strips;
// footprint/XCD = 2MB A + 2MB W = 4MB L2.
__global__ __launch_bounds__(256) void gemm_qv_kernel(
    const _Float16* __restrict__ Aq, const _Float16* __restrict__ Av,
    const _Float16* __restrict__ Wq, const _Float16* __restrict__ Wv,
    const float* __restrict__ bq, const float* __restrict__ bv,
    _Float16* __restrict__ q_out, _Float16* __restrict__ v_out)
{
    int id = blockIdx.x;
    int k8 = id & 7;
    int z  = k8 & 1;
    int y  = (k8 >> 1) * 16 + ((id >> 3) & 15);  // 0..63
    int x  = (id >> 7) & 7;                      // 0..7
    if (z) gemm_core<64, 1>(Av, Wv, bv, (void*)v_out, y * 64, x * 128);
    else   gemm_core<64, 0>(Aq, Wq, bq, (void*)q_out, y * 64, x * 128);
}

// 512 blocks. XCD k -> y in {8k..8k+7}: 1MB A + 2MB W per XCD.
__global__ __launch_bounds__(256) void gemm_o_kernel(
    const _Float16* __restrict__ A, const _Float16* __restrict__ W,
    const float* __restrict__ bias, float* __restrict__ outp)
{
    int id = blockIdx.x;
    int y = (id & 7) * 8 + ((id >> 3) & 7);      // 0..63
    int x = id >> 6;                             // 0..7
    gemm_core<64, 2>(A, W, bias, (void*)outp, y * 64, x * 128);
}

// ---------------- fused attention (S^T, static-max softmax, K == Q) -------------
// Block: 64 q-rows (4 waves x 16). 1-D grid: bh = blk&63 (XCD-local), qtile = blk>>6.
// Exchange-free PV: MFMA contracts over architectural k-slots, so the S^T C-layout
// P values (lane holds P[q=n16][k=t*16+quad*4+r]) feed the PV B-operand DIRECTLY;
// V's A-operand is read from LDS with the matching k-permutation (2x b64 per frag).
// No P LDS round-trip, no cross-lane exchange, zero conflicts.
__global__ __launch_bounds__(256) void attn_kernel(
    const _Float16* __restrict__ qb,   // (B,H,S,D) fp16
    const _Float16* __restrict__ vt,   // (B,H,D,S) fp16 (transposed)
    const float* __restrict__ rpk, const float* __restrict__ rpv,  // (5,64) fp32
    _Float16* __restrict__ attn_o)     // (B*S, H*D) fp16
{
    const int blk = blockIdx.x;
    const int bh = blk & 63;
    const int q0 = (blk >> 6) * 64;
    const int tid = threadIdx.x;
    const int wave = tid >> 6, lane = tid & 63;
    const int quad = lane >> 4, n16 = lane & 15;
    const int qw = q0 + wave * 16;
    const _Float16* Qh = qb + (size_t)bh * 1024 * 64;
    const _Float16* Vh = vt + (size_t)bh * 64 * 1024;

    __shared__ __align__(16) _Float16 Ks[2][64 * 64];
    __shared__ __align__(16) _Float16 Vs[2][64 * 64];
    __shared__ float rqs[4][16][5];

    const int rL = lane >> 3, c8 = lane & 7;
    const int lcs = c8 ^ rL;

    // prologue: stage tile 0 into buffer 0 (overlaps rc precompute below)
    #pragma unroll
    for (int p = 0; p < 2; p++) {
        int c = wave * 2 + p;
        int row = c * 8 + rL;
        async_copy16(Qh + (size_t)row * 64 + lcs * 8, &Ks[0][c * 512]);
        async_copy16(Vh + (size_t)row * 1024 + lcs * 8, &Vs[0][c * 512]);
    }

    // rc[t] = (dot(q_row, rpk[t]) - |q_row|^2) * 0.125 for this lane's own q-row
    {
        int m = lane >> 2, seg = lane & 3;
        const _Float16* qrow = Qh + (size_t)(qw + m) * 64 + seg * 16;
        v8h qa = *(const v8h*)(qrow);
        v8h qc = *(const v8h*)(qrow + 8);
        float qd[16];
        #pragma unroll
        for (int x = 0; x < 8; x++) { qd[x] = (float)qa[x]; qd[8 + x] = (float)qc[x]; }
        float qq = 0.f;
        #pragma unroll
        for (int x = 0; x < 16; x++) qq += qd[x] * qd[x];
        qq += __shfl_xor(qq, 1);
        qq += __shfl_xor(qq, 2);
        #pragma unroll
        for (int t = 0; t < 5; t++) {
            float s = 0.f;
            #pragma unroll
            for (int x = 0; x < 16; x++) s += qd[x] * rpk[t * 64 + seg * 16 + x];
            s += __shfl_xor(s, 1);
            s += __shfl_xor(s, 2);
            if (seg == 0) rqs[wave][m][t] = (s - qq) * 0.125f;
        }
    }

    // Q fragment (B-operand): B[n=q=lane&15][k=quad*8+j]
    v8h aq0 = *(const v8h*)(Qh + (size_t)(qw + n16) * 64 + quad * 8);
    v8h aq1 = *(const v8h*)(Qh + (size_t)(qw + n16) * 64 + 32 + quad * 8);

    __syncthreads();   // drains tile-0 staging; rqs visible

    float rc[5];
    #pragma unroll
    for (int t = 0; t < 5; t++) rc[t] = rqs[wave][n16][t];

    // bucket sums for this lane's q-row (index = rpk/rpv table row):
    // 4: diff>=2, 3: diff==1, 2: diff==0, 1: diff==-1, 0: diff<=-2
    float bkt[5] = {0.f, 0.f, 0.f, 0.f, 0.f};
    v4f O[4] = {};

    const int pphys0 = quad ^ (n16 & 7);
    const int pphys1 = (quad + 4) ^ (n16 & 7);
    const int xk = n16 & 7;
    const int vq = quad >> 1, vo = (quad & 1) * 4;

    for (int it = 0; it < 16; ++it) {
        const int cur = it & 1;
        const int kb = it * 64;
        if (it + 1 < 16) {                 // prefetch next tile into other buffer
            const int nxt = 1 - cur;
            const int kn = kb + 64;
            #pragma unroll
            for (int p = 0; p < 2; p++) {
                int c = wave * 2 + p;
                int row = c * 8 + rL;
                async_copy16(Qh + (size_t)(kn + row) * 64 + lcs * 8, &Ks[nxt][c * 512]);
                async_copy16(Vh + (size_t)row * 1024 + kn + lcs * 8, &Vs[nxt][c * 512]);
            }
        }

        // ---- scores S^T: lane owns q = qw+n16, k = t*16 + quad*4 + r ----
        int pkLo[4], pkHi[4];
        #pragma unroll
        for (int t = 0; t < 4; t++) {
            v8h ak0 = *(const v8h*)(&Ks[cur][(t * 16 + n16) * 64 + pphys0 * 8]);
            v8h ak1 = *(const v8h*)(&Ks[cur][(t * 16 + n16) * 64 + pphys1 * 8]);
            v4f s = {0.f, 0.f, 0.f, 0.f};
            s = MFMA_F16(ak0, aq0, s);
            s = MFMA_F16(ak1, aq1, s);
            const int dqt = qw - kb - t * 16;      // wave-uniform
            float pv[4];
            if (dqt >= 32) {                       // whole tile diff >= 2
                #pragma unroll
                for (int r = 0; r < 4; r++) {
                    float p = __expf(fmaf(s[r], 0.125f, rc[4]));
                    pv[r] = p; bkt[4] += p;
                }
            } else if (dqt <= -32) {               // whole tile diff <= -2
                #pragma unroll
                for (int r = 0; r < 4; r++) {
                    float p = __expf(fmaf(s[r], 0.125f, rc[0]));
                    pv[r] = p; bkt[0] += p;
                }
            } else {                               // near-diagonal tile
                #pragma unroll
                for (int r = 0; r < 4; r++) {
                    int diff = dqt + n16 - quad * 4 - r;
                    float rv = diff >= 2  ? rc[4]
                             : diff == 1  ? rc[3]
                             : diff == 0  ? rc[2]
                             : diff == -1 ? rc[1]
                                          : rc[0];
                    float p = __expf(fmaf(s[r], 0.125f, rv));
                    pv[r] = p;
                    bkt[4] += (diff >= 2)  ? p : 0.f;
                    bkt[3] += (diff == 1)  ? p : 0.f;
                    bkt[2] += (diff == 0)  ? p : 0.f;
                    bkt[1] += (diff == -1) ? p : 0.f;
                    bkt[0] += (diff <= -2) ? p : 0.f;
                }
            }
            pkLo[t] = __builtin_bit_cast(int, __builtin_amdgcn_cvt_pkrtz(pv[0], pv[1]));
            pkHi[t] = __builtin_bit_cast(int, __builtin_amdgcn_cvt_pkrtz(pv[2], pv[3]));
        }

        // ---- PV, exchange-free: P registers ARE the B-operand under the k-slot
        // permutation kg(quad,j) = (j>>2)*16 + quad*4 + (j&3) (+32 for frag 1).
        union { int d[4]; v8h v; } ub0, ub1;
        ub0.d[0] = pkLo[0]; ub0.d[1] = pkHi[0]; ub0.d[2] = pkLo[1]; ub0.d[3] = pkHi[1];
        ub1.d[0] = pkLo[2]; ub1.d[1] = pkHi[2]; ub1.d[2] = pkLo[3]; ub1.d[3] = pkHi[3];
        v8h bf0 = ub0.v, bf1 = ub1.v;

        #pragma unroll
        for (int dt = 0; dt < 4; dt++) {
            const int rowd = (dt * 16 + n16) * 64;
            v4h a0 = *(const v4h*)(&Vs[cur][rowd + ((vq     ^ xk) << 3) + vo]);
            v4h a1 = *(const v4h*)(&Vs[cur][rowd + (((vq+2) ^ xk) << 3) + vo]);
            v4h a2 = *(const v4h*)(&Vs[cur][rowd + (((vq+4) ^ xk) << 3) + vo]);
            v4h a3 = *(const v4h*)(&Vs[cur][rowd + (((vq+6) ^ xk) << 3) + vo]);
            O[dt] = MFMA_F16(cat4(a0, a1), bf0, O[dt]);   // O^T: row = d-local, col = q
            O[dt] = MFMA_F16(cat4(a2, a3), bf1, O[dt]);
        }

        __syncthreads();   // drains prefetch (flew across compute) + buffer handoff
    }

    // epilogue: reduce buckets across the 4 quads sharing this q-row
    #pragma unroll
    for (int t = 0; t < 5; t++) {
        bkt[t] += __shfl_xor(bkt[t], 16);
        bkt[t] += __shfl_xor(bkt[t], 32);
    }
    float l = bkt[0] + bkt[1] + bkt[2] + bkt[3] + bkt[4];
    float inv = 1.0f / l;
    int q = qw + n16;
    size_t orow = (size_t)((bh >> 4) * 1024 + q) * 1024 + (bh & 15) * 64;
    #pragma unroll
    for (int dt = 0; dt < 4; dt++) {
        int d0 = dt * 16 + quad * 4;
        v4h st;
        #pragma unroll
        for (int r = 0; r < 4; r++) {
            int d = d0 + r;
            float w2 = bkt[4] * rpv[4 * 64 + d] + bkt[3] * rpv[3 * 64 + d]
                     + bkt[2] * rpv[2 * 64 + d] + bkt[1] * rpv[1 * 64 + d]
                     + bkt[0] * rpv[0 * 64 + d];
            st[r] = (_Float16)((O[dt][r] + w2) * inv);
        }
        *(v4h*)(attn_o + orow + d0) = st;
    }
}

// ---------------- host launcher ----------------
extern "C" void kernel_launch(void* const* d_in, const int* in_sizes, int n_in,
                              void* d_out, int out_size, void* d_ws, size_t ws_size,
                              hipStream_t stream)
{
    const float* query = (const float*)d_in[0];
    // d_in[1] = key (unused: reference's k projection is dead code)
    const float* value = (const float*)d_in[2];
    const float* Wq = (const float*)d_in[3];
    const float* bq = (const float*)d_in[4];
    // d_in[5], d_in[6] = Wk, bk (unused)
    const float* Wv = (const float*)d_in[7];
    const float* bv = (const float*)d_in[8];
    const float* Wo = (const float*)d_in[9];
    const float* bo = (const float*)d_in[10];
    const float* rpk = (const float*)d_in[11];
    const float* rpv = (const float*)d_in[12];
    float* out = (float*)d_out;

    char* ws = (char*)d_ws;
    const size_t MB = 1024 * 1024;
    _Float16* q_bhsd = (_Float16*)(ws);             // 8 MB: q proj (B,H,S,D)
    _Float16* v_t    = (_Float16*)(ws + 8 * MB);    // 8 MB: v proj (B,H,D,S)
    _Float16* q16    = (_Float16*)(ws + 16 * MB);   // 8 MB: query fp16
    _Float16* attn_o = (_Float16*)(ws + 16 * MB);   // aliases q16 (dead after gemm_qv)
    _Float16* v16    = (_Float16*)(ws + 24 * MB);   // 8 MB: value fp16
    _Float16* wq16   = (_Float16*)(ws + 32 * MB);   // 2 MB
    _Float16* wv16   = (_Float16*)(ws + 34 * MB);   // 2 MB
    _Float16* wo16   = (_Float16*)(ws + 36 * MB);   // 2 MB   (total 38 MB)

    cvt5_kernel<<<dim3(4096, 5), 256, 0, stream>>>(
        query, value, Wq, Wv, Wo, q16, v16, wq16, wv16, wo16,
        4096 * 1024, 4096 * 1024, 1024 * 1024, 1024 * 1024, 1024 * 1024);

    gemm_qv_kernel<<<dim3(1024), 256, 0, stream>>>(
        q16, v16, wq16, wv16, bq, bv, q_bhsd, v_t);

    attn_kernel<<<dim3(1024), 256, 0, stream>>>(q_bhsd, v_t, rpk, rpv, attn_o);

    gemm_o_kernel<<<dim3(512), 256, 0, stream>>>(attn_o, wo16, bo, out);
}

// Round 7
// 197.952 us; speedup vs baseline: 1.0392x; 1.0392x over previous
//
#include <hip/hip_runtime.h>

// B=4, S=1024, E=1024, H=16, D=64. All GEMMs are 4096x1024x1024 (A MxK row-major,
// W NxK row-major => C = A * W^T + bias).

typedef _Float16 v8h __attribute__((ext_vector_type(8)));
typedef _Float16 v4h __attribute__((ext_vector_type(4)));
typedef float    v4f __attribute__((ext_vector_type(4)));

#define MFMA_F16(A_, B_, C_) __builtin_amdgcn_mfma_f32_16x16x32_f16(A_, B_, C_, 0, 0, 0)

__device__ __forceinline__ void async_copy16(const void* g, void* l) {
    __builtin_amdgcn_global_load_lds(
        (const __attribute__((address_space(1))) void*)g,
        (__attribute__((address_space(3))) void*)l, 16, 0, 0);
}

// ---------------- fp32 -> fp16 conversion (5 tensors, one launch) ----------------
__global__ __launch_bounds__(256) void cvt5_kernel(
    const float* __restrict__ s0, const float* __restrict__ s1,
    const float* __restrict__ s2, const float* __restrict__ s3,
    const float* __restrict__ s4,
    _Float16* __restrict__ d0, _Float16* __restrict__ d1,
    _Float16* __restrict__ d2, _Float16* __restrict__ d3,
    _Float16* __restrict__ d4,
    int n0, int n1, int n2, int n3, int n4)
{
    const float* s; _Float16* d; int n;
    switch (blockIdx.y) {
        case 0:  s = s0; d = d0; n = n0; break;
        case 1:  s = s1; d = d1; n = n1; break;
        case 2:  s = s2; d = d2; n = n2; break;
        case 3:  s = s3; d = d3; n = n3; break;
        default: s = s4; d = d4; n = n4; break;
    }
    int i = (blockIdx.x * 256 + threadIdx.x) * 4;
    if (i >= n) return;
    float4 f = *(const float4*)(s + i);
    v4h o = { (_Float16)f.x, (_Float16)f.y, (_Float16)f.z, (_Float16)f.w };
    *(v4h*)(d + i) = o;
}

// ---------------- shared GEMM core: C = A * W^T + bias ----------------
// TM x 128 tile, BK=64, 256 threads (4 waves). XOR-swizzled LDS (16B chunk c of
// row r holds logical chunk c ^ (r&7)); staged via global_load_lds 16B/lane.
// Epilogue via per-wave LDS scratch -> coalesced stores.
// MODE 0: fp16 (B,H,S,D).
// MODE 1: fp16 transposed (B,H,D,S) with PER-64-BLOCK k-permutation
//         p(k) = ((k>>2)&3)*8 + ((k>>4)&1)*4 + (k&3) + 32*(k>>5), so the attention
//         kernel's PV V-fragment is a contiguous conflict-free b128 read.
// MODE 2: fp32 (M,N), TM=64 (wave tile 64x32).
template<int TM, int MODE>
__device__ __forceinline__ void gemm_core(const _Float16* __restrict__ A,
                                          const _Float16* __restrict__ W,
                                          const float* __restrict__ bias,
                                          void* __restrict__ outp,
                                          int row0, int col0)
{
    constexpr int WCOLS = (TM == 128) ? 64 : 32;
    constexpr int NJ = WCOLS / 16;
    constexpr int SC_H = (MODE == 2) ? 4096 : 64 * WCOLS;  // per-wave scratch (halves)
    constexpr int STG_H = (TM + 128) * 64;
    constexpr int TOT_H = (STG_H > 4 * SC_H) ? STG_H : 4 * SC_H;
    __shared__ __align__(16) _Float16 smem[TOT_H];
    _Float16* As = smem;
    _Float16* Bs = smem + TM * 64;

    const int tid  = threadIdx.x;
    const int wave = tid >> 6, lane = tid & 63;
    const int quad = lane >> 4, n16 = lane & 15;
    const int wm = (TM == 128) ? (wave >> 1) : 0;
    const int wn = (TM == 128) ? (wave & 1) : wave;
    const int rL = lane >> 3, c8 = lane & 7;
    const int lcs = c8 ^ rL;

    v4f acc[4][NJ] = {};

    for (int kb = 0; kb < 1024; kb += 64) {
        __syncthreads();
        #pragma unroll
        for (int p = 0; p < TM / 32; p++) {
            int rg = wave * (TM / 32) + p;
            int row = rg * 8 + rL;
            async_copy16(A + (size_t)(row0 + row) * 1024 + kb + lcs * 8, &As[rg * 512]);
        }
        #pragma unroll
        for (int p = 0; p < 4; p++) {
            int rg = wave * 4 + p;
            int row = rg * 8 + rL;
            async_copy16(W + (size_t)(col0 + row) * 1024 + kb + lcs * 8, &Bs[rg * 512]);
        }
        __syncthreads();
        #pragma unroll
        for (int ks = 0; ks < 64; ks += 32) {
            const int pc = ((ks >> 3) + quad) ^ (n16 & 7);
            v8h af[4], bf[NJ];
            #pragma unroll
            for (int i = 0; i < 4; i++)
                af[i] = *(const v8h*)(&As[(wm * 64 + i * 16 + n16) * 64 + pc * 8]);
            #pragma unroll
            for (int j = 0; j < NJ; j++)
                bf[j] = *(const v8h*)(&Bs[(wn * WCOLS + j * 16 + n16) * 64 + pc * 8]);
            #pragma unroll
            for (int i = 0; i < 4; i++)
                #pragma unroll
                for (int j = 0; j < NJ; j++)
                    acc[i][j] = MFMA_F16(af[i], bf[j], acc[i][j]);
        }
    }

    __syncthreads();                       // staged tiles dead; reuse LDS as scratch
    const int b     = (row0 + wm * 64) >> 10;
    const int srow0 = (row0 + wm * 64) & 1023;
    const int C0    = col0 + wn * WCOLS;

    if (MODE == 0) {                       // [s][d] scratch, coalesced (B,H,S,D) stores
        _Float16* sc = smem + wave * SC_H;
        #pragma unroll
        for (int i = 0; i < 4; i++)
            #pragma unroll
            for (int j = 0; j < NJ; j++)
                #pragma unroll
                for (int r = 0; r < 4; r++) {
                    int rowL = i * 16 + quad * 4 + r, colL = j * 16 + n16;
                    float v = acc[i][j][r] + bias[C0 + colL];
                    sc[rowL * 64 + (((colL >> 3) ^ (rowL & 7)) << 3) + (colL & 7)] = (_Float16)v;
                }
        int h = C0 >> 6;
        #pragma unroll
        for (int it = 0; it < 8; it++) {
            int rowR = it * 8 + (lane >> 3), cR = lane & 7;
            v8h val = *(const v8h*)(&sc[rowR * 64 + ((cR ^ (rowR & 7)) << 3)]);
            *(v8h*)((_Float16*)outp +
                    (((size_t)(b * 16 + h) * 1024 + srow0 + rowR) << 6) + cR * 8) = val;
        }
    } else if (MODE == 1) {                // [d][s] scratch, permuted (B,H,D,S) stores
        _Float16* sc = smem + wave * SC_H;
        #pragma unroll
        for (int i = 0; i < 4; i++)
            #pragma unroll
            for (int j = 0; j < NJ; j++) {
                int colL = j * 16 + n16;
                int c16 = i * 2 + (quad >> 1);
                v4h pk;
                #pragma unroll
                for (int r = 0; r < 4; r++)
                    pk[r] = (_Float16)(acc[i][j][r] + bias[C0 + colL]);
                *(v4h*)(&sc[colL * 64 + ((c16 ^ (colL & 7)) << 3) + (quad & 1) * 4]) = pk;
            }
        #pragma unroll
        for (int it = 0; it < 8; it++) {
            int dR = it * 8 + (lane >> 3), g = lane & 7;
            v8h val = *(const v8h*)(&sc[dR * 64 + ((g ^ (dR & 7)) << 3)]);
            int cg = C0 + dR;
            int h = cg >> 6, dl = cg & 63;
            _Float16* base = (_Float16*)outp +
                             ((size_t)((b * 16 + h) * 64 + dl) << 10) + srow0;
            // k-block permutation: original s-cols [8g..8g+7] scatter as two v4h
            int a4  = ((g >> 1) & 1) * 4, b32 = (g >> 2) * 32;
            int p0  = b32 + ((2 * g) & 3) * 8 + a4;
            int p1  = b32 + ((2 * g + 1) & 3) * 8 + a4;
            v4h lo = __builtin_shufflevector(val, val, 0, 1, 2, 3);
            v4h hi = __builtin_shufflevector(val, val, 4, 5, 6, 7);
            *(v4h*)(base + p0) = lo;
            *(v4h*)(base + p1) = hi;
        }
    } else {                               // MODE 2 (TM=64): fp32 [m][n], wave tile 64x32
        float* sc = (float*)smem + wave * 2048;
        #pragma unroll
        for (int i = 0; i < 4; i++)
            #pragma unroll
            for (int j = 0; j < 2; j++)
                #pragma unroll
                for (int r = 0; r < 4; r++) {
                    int rowL = i * 16 + quad * 4 + r, colL = j * 16 + n16;
                    sc[rowL * 32 + (((colL >> 2) ^ (rowL & 7)) << 2) + (colL & 3)] =
                        acc[i][j][r] + bias[col0 + wn * 32 + colL];
                }
        #pragma unroll
        for (int it = 0; it < 8; it++) {
            int rowR = it * 8 + (lane >> 3), cR = lane & 7;
            v4f val = *(const v4f*)(&sc[rowR * 32 + ((cR ^ (rowR & 7)) << 2)]);
            *(v4f*)((float*)outp + (size_t)(row0 + rowR) * 1024 + col0 + wn * 32 + cR * 4) = val;
        }
    }
}

// 512 blocks, TM=128. XCD swizzle keyed on A row-strip.
__global__ __launch_bounds__(256) void gemm_qv_kernel(
    const _Float16* __restrict__ Aq, const _Float16* __restrict__ Av,
    const _Float16* __restrict__ Wq, const _Float16* __restrict__ Wv,
    const float* __restrict__ bq, const float* __restrict__ bv,
    _Float16* __restrict__ q_out, _Float16* __restrict__ v_out)
{
    int id = blockIdx.x;
    int y = (id & 7) | (((id >> 3) & 3) << 3);   // 0..31
    int x = (id >> 5) & 7;                       // 0..7
    int z = id >> 8;                             // 0..1
    if (z) gemm_core<128, 1>(Av, Wv, bv, (void*)v_out, y * 128, x * 128);
    else   gemm_core<128, 0>(Aq, Wq, bq, (void*)q_out, y * 128, x * 128);
}

// 512 blocks, TM=64, fp32 output.
__global__ __launch_bounds__(256) void gemm_o_kernel(
    const _Float16* __restrict__ A, const _Float16* __restrict__ W,
    const float* __restrict__ bias, float* __restrict__ outp)
{
    int id = blockIdx.x;
    int y = (id & 7) * 8 + ((id >> 3) & 7);      // 0..63
    int x = id >> 6;                             // 0..7
    gemm_core<64, 2>(A, W, bias, (void*)outp, y * 64, x * 128);
}

// ---------------- fused attention (S^T, static-max softmax, K == Q) -------------
// Block: 64 q-rows (4 waves x 16). 1-D grid: bh = blk&63 (XCD-local), qtile = blk>>6.
// Exchange-free PV: the S^T C-layout P values feed the PV B-operand directly from
// registers; v_t is stored k-permuted by the producer so the matching V A-fragment
// is a contiguous conflict-free b128 LDS read (same pattern as the K reads).
__global__ __launch_bounds__(256) void attn_kernel(
    const _Float16* __restrict__ qb,   // (B,H,S,D) fp16
    const _Float16* __restrict__ vt,   // (B,H,D,S) fp16, k-permuted per 64-block
    const float* __restrict__ rpk, const float* __restrict__ rpv,  // (5,64) fp32
    _Float16* __restrict__ attn_o)     // (B*S, H*D) fp16
{
    const int blk = blockIdx.x;
    const int bh = blk & 63;
    const int q0 = (blk >> 6) * 64;
    const int tid = threadIdx.x;
    const int wave = tid >> 6, lane = tid & 63;
    const int quad = lane >> 4, n16 = lane & 15;
    const int qw = q0 + wave * 16;
    const _Float16* Qh = qb + (size_t)bh * 1024 * 64;
    const _Float16* Vh = vt + (size_t)bh * 64 * 1024;

    __shared__ __align__(16) _Float16 Ks[2][64 * 64];
    __shared__ __align__(16) _Float16 Vs[2][64 * 64];
    __shared__ float rqs[4][16][5];

    const int rL = lane >> 3, c8 = lane & 7;
    const int lcs = c8 ^ rL;

    // prologue: stage tile 0 into buffer 0 (overlaps rc precompute below)
    #pragma unroll
    for (int p = 0; p < 2; p++) {
        int c = wave * 2 + p;
        int row = c * 8 + rL;
        async_copy16(Qh + (size_t)row * 64 + lcs * 8, &Ks[0][c * 512]);
        async_copy16(Vh + (size_t)row * 1024 + lcs * 8, &Vs[0][c * 512]);
    }

    // rc[t] = (dot(q_row, rpk[t]) - |q_row|^2) * 0.125 for this lane's own q-row
    {
        int m = lane >> 2, seg = lane & 3;
        const _Float16* qrow = Qh + (size_t)(qw + m) * 64 + seg * 16;
        v8h qa = *(const v8h*)(qrow);
        v8h qc = *(const v8h*)(qrow + 8);
        float qd[16];
        #pragma unroll
        for (int x = 0; x < 8; x++) { qd[x] = (float)qa[x]; qd[8 + x] = (float)qc[x]; }
        float qq = 0.f;
        #pragma unroll
        for (int x = 0; x < 16; x++) qq += qd[x] * qd[x];
        qq += __shfl_xor(qq, 1);
        qq += __shfl_xor(qq, 2);
        #pragma unroll
        for (int t = 0; t < 5; t++) {
            float s = 0.f;
            #pragma unroll
            for (int x = 0; x < 16; x++) s += qd[x] * rpk[t * 64 + seg * 16 + x];
            s += __shfl_xor(s, 1);
            s += __shfl_xor(s, 2);
            if (seg == 0) rqs[wave][m][t] = (s - qq) * 0.125f;
        }
    }

    // Q fragment (B-operand): B[n=q=lane&15][k=quad*8+j]
    v8h aq0 = *(const v8h*)(Qh + (size_t)(qw + n16) * 64 + quad * 8);
    v8h aq1 = *(const v8h*)(Qh + (size_t)(qw + n16) * 64 + 32 + quad * 8);

    __syncthreads();   // drains tile-0 staging; rqs visible

    float rc[5];
    #pragma unroll
    for (int t = 0; t < 5; t++) rc[t] = rqs[wave][n16][t];

    // bucket sums for this lane's q-row (index = rpk/rpv table row):
    // 4: diff>=2, 3: diff==1, 2: diff==0, 1: diff==-1, 0: diff<=-2
    float bkt[5] = {0.f, 0.f, 0.f, 0.f, 0.f};
    v4f O[4] = {};

    const int pphys0 = quad ^ (n16 & 7);
    const int pphys1 = (quad + 4) ^ (n16 & 7);

    for (int it = 0; it < 16; ++it) {
        const int cur = it & 1;
        const int kb = it * 64;
        if (it + 1 < 16) {                 // prefetch next tile into other buffer
            const int nxt = 1 - cur;
            const int kn = kb + 64;
            #pragma unroll
            for (int p = 0; p < 2; p++) {
                int c = wave * 2 + p;
                int row = c * 8 + rL;
                async_copy16(Qh + (size_t)(kn + row) * 64 + lcs * 8, &Ks[nxt][c * 512]);
                async_copy16(Vh + (size_t)row * 1024 + kn + lcs * 8, &Vs[nxt][c * 512]);
            }
        }

        // ---- scores S^T: lane owns q = qw+n16, k = t*16 + quad*4 + r ----
        int pkLo[4], pkHi[4];
        #pragma unroll
        for (int t = 0; t < 4; t++) {
            v8h ak0 = *(const v8h*)(&Ks[cur][(t * 16 + n16) * 64 + pphys0 * 8]);
            v8h ak1 = *(const v8h*)(&Ks[cur][(t * 16 + n16) * 64 + pphys1 * 8]);
            v4f s = {0.f, 0.f, 0.f, 0.f};
            s = MFMA_F16(ak0, aq0, s);
            s = MFMA_F16(ak1, aq1, s);
            const int dqt = qw - kb - t * 16;      // wave-uniform
            float pv[4];
            if (dqt >= 32) {                       // whole tile diff >= 2
                #pragma unroll
                for (int r = 0; r < 4; r++) {
                    float p = __expf(fmaf(s[r], 0.125f, rc[4]));
                    pv[r] = p; bkt[4] += p;
                }
            } else if (dqt <= -32) {               // whole tile diff <= -2
                #pragma unroll
                for (int r = 0; r < 4; r++) {
                    float p = __expf(fmaf(s[r], 0.125f, rc[0]));
                    pv[r] = p; bkt[0] += p;
                }
            } else {                               // near-diagonal tile
                #pragma unroll
                for (int r = 0; r < 4; r++) {
                    int diff = dqt + n16 - quad * 4 - r;
                    float rv = diff >= 2  ? rc[4]
                             : diff == 1  ? rc[3]
                             : diff == 0  ? rc[2]
                             : diff == -1 ? rc[1]
                                          : rc[0];
                    float p = __expf(fmaf(s[r], 0.125f, rv));
                    pv[r] = p;
                    bkt[4] += (diff >= 2)  ? p : 0.f;
                    bkt[3] += (diff == 1)  ? p : 0.f;
                    bkt[2] += (diff == 0)  ? p : 0.f;
                    bkt[1] += (diff == -1) ? p : 0.f;
                    bkt[0] += (diff <= -2) ? p : 0.f;
                }
            }
            pkLo[t] = __builtin_bit_cast(int, __builtin_amdgcn_cvt_pkrtz(pv[0], pv[1]));
            pkHi[t] = __builtin_bit_cast(int, __builtin_amdgcn_cvt_pkrtz(pv[2], pv[3]));
        }

        // ---- PV: P registers ARE the B-operand (k-slot order k = t*16+quad*4+r);
        // V A-operand comes as contiguous b128 thanks to producer-side permutation.
        union { int d[4]; v8h v; } ub0, ub1;
        ub0.d[0] = pkLo[0]; ub0.d[1] = pkHi[0]; ub0.d[2] = pkLo[1]; ub0.d[3] = pkHi[1];
        ub1.d[0] = pkLo[2]; ub1.d[1] = pkHi[2]; ub1.d[2] = pkLo[3]; ub1.d[3] = pkHi[3];
        v8h bf0 = ub0.v, bf1 = ub1.v;

        #pragma unroll
        for (int dt = 0; dt < 4; dt++) {
            const int rowd = (dt * 16 + n16) * 64;
            v8h av0 = *(const v8h*)(&Vs[cur][rowd + pphys0 * 8]);
            v8h av1 = *(const v8h*)(&Vs[cur][rowd + pphys1 * 8]);
            O[dt] = MFMA_F16(av0, bf0, O[dt]);    // O^T: row = d-local, col = q
            O[dt] = MFMA_F16(av1, bf1, O[dt]);
        }

        __syncthreads();   // drains prefetch (flew across compute) + buffer handoff
    }

    // epilogue: reduce buckets across the 4 quads sharing this q-row
    #pragma unroll
    for (int t = 0; t < 5; t++) {
        bkt[t] += __shfl_xor(bkt[t], 16);
        bkt[t] += __shfl_xor(bkt[t], 32);
    }
    float l = bkt[0] + bkt[1] + bkt[2] + bkt[3] + bkt[4];
    float inv = 1.0f / l;
    int q = qw + n16;
    size_t orow = (size_t)((bh >> 4) * 1024 + q) * 1024 + (bh & 15) * 64;
    #pragma unroll
    for (int dt = 0; dt < 4; dt++) {
        int d0 = dt * 16 + quad * 4;
        v4h st;
        #pragma unroll
        for (int r = 0; r < 4; r++) {
            int d = d0 + r;
            float w2 = bkt[4] * rpv[4 * 64 + d] + bkt[3] * rpv[3 * 64 + d]
                     + bkt[2] * rpv[2 * 64 + d] + bkt[1] * rpv[1 * 64 + d]
                     + bkt[0] * rpv[0 * 64 + d];
            st[r] = (_Float16)((O[dt][r] + w2) * inv);
        }
        *(v4h*)(attn_o + orow + d0) = st;
    }
}

// ---------------- host launcher ----------------
extern "C" void kernel_launch(void* const* d_in, const int* in_sizes, int n_in,
                              void* d_out, int out_size, void* d_ws, size_t ws_size,
                              hipStream_t stream)
{
    const float* query = (const float*)d_in[0];
    // d_in[1] = key (unused: reference's k projection is dead code)
    const float* value = (const float*)d_in[2];
    const float* Wq = (const float*)d_in[3];
    const float* bq = (const float*)d_in[4];
    // d_in[5], d_in[6] = Wk, bk (unused)
    const float* Wv = (const float*)d_in[7];
    const float* bv = (const float*)d_in[8];
    const float* Wo = (const float*)d_in[9];
    const float* bo = (const float*)d_in[10];
    const float* rpk = (const float*)d_in[11];
    const float* rpv = (const float*)d_in[12];
    float* out = (float*)d_out;

    char* ws = (char*)d_ws;
    const size_t MB = 1024 * 1024;
    _Float16* q_bhsd = (_Float16*)(ws);             // 8 MB: q proj (B,H,S,D)
    _Float16* v_t    = (_Float16*)(ws + 8 * MB);    // 8 MB: v proj (B,H,D,S) permuted
    _Float16* q16    = (_Float16*)(ws + 16 * MB);   // 8 MB: query fp16
    _Float16* attn_o = (_Float16*)(ws + 16 * MB);   // aliases q16 (dead after gemm_qv)
    _Float16* v16    = (_Float16*)(ws + 24 * MB);   // 8 MB: value fp16
    _Float16* wq16   = (_Float16*)(ws + 32 * MB);   // 2 MB
    _Float16* wv16   = (_Float16*)(ws + 34 * MB);   // 2 MB
    _Float16* wo16   = (_Float16*)(ws + 36 * MB);   // 2 MB   (total 38 MB)

    cvt5_kernel<<<dim3(4096, 5), 256, 0, stream>>>(
        query, value, Wq, Wv, Wo, q16, v16, wq16, wv16, wo16,
        4096 * 1024, 4096 * 1024, 1024 * 1024, 1024 * 1024, 1024 * 1024);

    gemm_qv_kernel<<<dim3(512), 256, 0, stream>>>(
        q16, v16, wq16, wv16, bq, bv, q_bhsd, v_t);

    attn_kernel<<<dim3(1024), 256, 0, stream>>>(q_bhsd, v_t, rpk, rpv, attn_o);

    gemm_o_kernel<<<dim3(512), 256, 0, stream>>>(attn_o, wo16, bo, out);
}